// Round 2
// baseline (5928.842 us; speedup 1.0000x reference)
//
#include <hip/hip_runtime.h>
#include <hip/hip_bf16.h>

#define RB 16
#define RC 32
#define RN 512
#define RROWS (RB*RC*RN)   // 262144

__device__ __forceinline__ float gelu_tanh(float x) {
    float u = 0.7978845608028654f * (x + 0.044715f * x * x * x);
    return 0.5f * x * (1.0f + tanhf(u));
}

// ---------------- DFT twiddle tables ----------------
// rfft T: [T][2H] cols 0..H-1 = cos(2pi h t/T), cols H..2H-1 = -sin
// irfft T: [2H][T] rows 0..H-1 = w_h cos /T, rows H..2H-1 = -w_h sin /T
//   (rows h=0 and h=Nyquist of the -sin block are identically zero -> numpy
//    irfft's "ignore imag of DC/Nyquist" semantics fall out automatically)
__global__ void init_tables_k(float* rf192, float* irf192, float* rf96, float* irf96) {
    int i = blockIdx.x * blockDim.x + threadIdx.x;
    const float PI2 = 6.283185307179586f;
    if (i < 192*194) {
        int t = i / 194, col = i % 194;
        int h = (col < 97) ? col : col - 97;
        float th = PI2 * (float)((h * t) % 192) / 192.0f;
        float s, c; sincosf(th, &s, &c);
        rf192[i] = (col < 97) ? c : -s;
    } else if (i < 192*194 + 194*192) {
        int j = i - 192*194;
        int row = j / 192, t = j % 192;
        int h = (row < 97) ? row : row - 97;
        float w = (h == 0 || h == 96) ? 1.0f : 2.0f;
        float th = PI2 * (float)((h * t) % 192) / 192.0f;
        float s, c; sincosf(th, &s, &c);
        irf192[j] = ((row < 97) ? w * c : -w * s) * (1.0f/192.0f);
    } else if (i < 192*194 + 194*192 + 96*98) {
        int j = i - (192*194 + 194*192);
        int t = j / 98, col = j % 98;
        int h = (col < 49) ? col : col - 49;
        float th = PI2 * (float)((h * t) % 96) / 96.0f;
        float s, c; sincosf(th, &s, &c);
        rf96[j] = (col < 49) ? c : -s;
    } else if (i < 192*194 + 194*192 + 96*98 + 98*96) {
        int j = i - (192*194 + 194*192 + 96*98);
        int row = j / 96, t = j % 96;
        int h = (row < 49) ? row : row - 49;
        float w = (h == 0 || h == 48) ? 1.0f : 2.0f;
        float th = PI2 * (float)((h * t) % 96) / 96.0f;
        float s, c; sincosf(th, &s, &c);
        irf96[j] = ((row < 49) ? w * c : -w * s) * (1.0f/96.0f);
    }
}

// ---------------- generic fp32 GEMM ----------------
// C[M x Nc] = A[M x K] @ B[K x Nc]
// DUAL: C = (A@B1) * gelu(A@B2)
// EPI: 0 plain store; 1 += addend[M x Nc]; 2 += bias[Nc]
template<bool DUAL, int EPI>
__global__ __launch_bounds__(256) void gemm_k(
    const float* __restrict__ Ap, const float* __restrict__ B1p, const float* __restrict__ B2p,
    float* __restrict__ Cp, const float* __restrict__ Xp,
    int M, int Nc, int K)
{
    __shared__ __align__(16) float As[16][64];
    __shared__ __align__(16) float Bs[16][64];
    __shared__ __align__(16) float Bs2[DUAL ? 16 : 1][64];

    const int tid = threadIdx.x;
    const int tx = tid & 15, ty = tid >> 4;
    const int m0 = blockIdx.y * 64, n0 = blockIdx.x * 64;

    float acc[4][4] = {{0.f}};
    float acc2[4][4] = {{0.f}};

    const int am = tid >> 2;          // 0..63 row within tile
    const int ak = (tid & 3) * 4;     // 0,4,8,12

    for (int k0 = 0; k0 < K; k0 += 16) {
        #pragma unroll
        for (int j = 0; j < 4; ++j) {
            int kk = ak + j;
            float v = 0.f;
            if (k0 + kk < K) v = Ap[(size_t)(m0 + am) * K + (k0 + kk)];
            As[kk][am] = v;
        }
        #pragma unroll
        for (int j = 0; j < 4; ++j) {
            int lin = tid + j * 256;
            int kk = lin >> 6, n = lin & 63;
            float v = 0.f, v2 = 0.f;
            if (k0 + kk < K && n0 + n < Nc) {
                size_t idx = (size_t)(k0 + kk) * Nc + (n0 + n);
                v = B1p[idx];
                if (DUAL) v2 = B2p[idx];
            }
            Bs[kk][n] = v;
            if (DUAL) Bs2[kk][n] = v2;
        }
        __syncthreads();
        #pragma unroll
        for (int kk = 0; kk < 16; ++kk) {
            const float4 a4 = *reinterpret_cast<const float4*>(&As[kk][ty * 4]);
            const float4 b4 = *reinterpret_cast<const float4*>(&Bs[kk][tx * 4]);
            const float av[4] = {a4.x, a4.y, a4.z, a4.w};
            const float bv[4] = {b4.x, b4.y, b4.z, b4.w};
            float b2v[4] = {0.f, 0.f, 0.f, 0.f};
            if (DUAL) {
                const float4 c4 = *reinterpret_cast<const float4*>(&Bs2[kk][tx * 4]);
                b2v[0] = c4.x; b2v[1] = c4.y; b2v[2] = c4.z; b2v[3] = c4.w;
            }
            #pragma unroll
            for (int ii = 0; ii < 4; ++ii)
                #pragma unroll
                for (int jj = 0; jj < 4; ++jj) {
                    acc[ii][jj] += av[ii] * bv[jj];
                    if (DUAL) acc2[ii][jj] += av[ii] * b2v[jj];
                }
        }
        __syncthreads();
    }

    #pragma unroll
    for (int ii = 0; ii < 4; ++ii) {
        int row = m0 + ty * 4 + ii;
        #pragma unroll
        for (int jj = 0; jj < 4; ++jj) {
            int col = n0 + tx * 4 + jj;
            if (col >= Nc) continue;
            size_t idx = (size_t)row * Nc + col;
            float v = acc[ii][jj];
            if (DUAL) v = v * gelu_tanh(acc2[ii][jj]);
            if (EPI == 1) v += Xp[idx];
            if (EPI == 2) v += Xp[col];
            Cp[idx] = v;
        }
    }
}

// ---------------- channel->latent spectral mixing ----------------
// out[b,l,n,h]_re = (sum_c Fr[b,c,n,h] Gc[c,l]) * Lc[l,h] ; imag with Gt,Lt
__global__ __launch_bounds__(128) void chanmix_k(
    const float* __restrict__ Fin, float* __restrict__ Fout,
    const float* __restrict__ Gc, const float* __restrict__ Lc,
    const float* __restrict__ Gt, const float* __restrict__ Lt)
{
    __shared__ float sGc[1024], sGt[1024];
    for (int j = threadIdx.x; j < 1024; j += 128) {
        sGc[j] = Gc[j];
        sGt[j] = Gt[j];
    }
    __syncthreads();

    int i = blockIdx.x * blockDim.x + threadIdx.x;
    if (i >= RB * RN * 97) return;
    int h = i % 97; int n = (i / 97) % RN; int b = i / (97 * RN);
    size_t base = ((size_t)b * RC * RN + n) * 194;
    const size_t cs = (size_t)RN * 194;

    float acc[32];
    #pragma unroll
    for (int l = 0; l < 32; ++l) acc[l] = 0.f;
    for (int c = 0; c < 32; ++c) {
        float v = Fin[base + (size_t)c * cs + h];
        #pragma unroll
        for (int l = 0; l < 32; ++l) acc[l] += v * sGc[c * 32 + l];
    }
    #pragma unroll
    for (int l = 0; l < 32; ++l)
        Fout[base + (size_t)l * cs + h] = acc[l] * Lc[l * 97 + h];

    #pragma unroll
    for (int l = 0; l < 32; ++l) acc[l] = 0.f;
    for (int c = 0; c < 32; ++c) {
        float v = Fin[base + (size_t)c * cs + 97 + h];
        #pragma unroll
        for (int l = 0; l < 32; ++l) acc[l] += v * sGt[c * 32 + l];
    }
    #pragma unroll
    for (int l = 0; l < 32; ++l)
        Fout[base + (size_t)l * cs + 97 + h] = acc[l] * Lt[l * 97 + h];
}

// ---------------- attn-gate pipeline ----------------
__global__ __launch_bounds__(256) void meanf_k(const float* __restrict__ z, float* __restrict__ feat, int T) {
    int bc = blockIdx.x; int b = bc >> 5, c = bc & 31;
    int t = threadIdx.x; if (t >= T) return;
    const float* p = z + (size_t)bc * RN * T + t;
    float acc = 0.f;
    #pragma unroll 8
    for (int n = 0; n < RN; ++n) acc += p[(size_t)n * T];
    feat[((size_t)b * T + t) * 32 + c] = acc * (1.0f / RN);
}

__global__ __launch_bounds__(256) void qk_k(const float* __restrict__ feat,
    const float* __restrict__ Wq, const float* __restrict__ Wk,
    float* __restrict__ qb, float* __restrict__ kb, int T)
{
    int i = blockIdx.x * blockDim.x + threadIdx.x;
    if (i >= 16 * T * 64) return;
    int e = i & 63; int t = (i >> 6) % T; int b = i / (64 * T);
    const float* f = feat + ((size_t)b * T + t) * 32;
    float q = 0.f, k = 0.f;
    #pragma unroll
    for (int c = 0; c < 32; ++c) {
        float fv = f[c];
        q += fv * Wq[c * 64 + e];
        k += fv * Wk[c * 64 + e];
    }
    qb[i] = q; kb[i] = k;
}

// one block per (b,t); stores 1+gelu(softmax_diag)
__global__ __launch_bounds__(64) void gate_k(const float* __restrict__ qb, const float* __restrict__ kb,
                                             float* __restrict__ gate, int T)
{
    __shared__ float s[192];
    int b = blockIdx.x / T, t = blockIdx.x % T;
    int lane = threadIdx.x;
    float qe = qb[((size_t)b * T + t) * 64 + lane];
    for (int t2 = 0; t2 < T; ++t2) {
        float prod = qe * kb[((size_t)b * T + t2) * 64 + lane];
        #pragma unroll
        for (int off = 32; off > 0; off >>= 1) prod += __shfl_xor(prod, off);
        if (lane == 0) s[t2] = prod * 0.125f;
    }
    __syncthreads();
    float m = -1e30f;
    for (int t2 = lane; t2 < T; t2 += 64) m = fmaxf(m, s[t2]);
    #pragma unroll
    for (int off = 32; off > 0; off >>= 1) m = fmaxf(m, __shfl_xor(m, off));
    float sum = 0.f;
    for (int t2 = lane; t2 < T; t2 += 64) sum += __expf(s[t2] - m);
    #pragma unroll
    for (int off = 32; off > 0; off >>= 1) sum += __shfl_xor(sum, off);
    if (lane == 0) {
        float wv = __expf(s[t] - m) / sum;
        gate[b * T + t] = 1.0f + gelu_tanh(wv);
    }
}

__global__ __launch_bounds__(256) void scale_k(float* __restrict__ z, const float* __restrict__ gate, int T) {
    size_t i = (size_t)blockIdx.x * blockDim.x + threadIdx.x;
    if (i >= (size_t)RROWS * T) return;
    int t = (int)(i % T);
    int b = (int)(i / ((size_t)T * RC * RN));
    z[i] *= gate[b * T + t];
}

// ---------------- misc elementwise ----------------
__global__ __launch_bounds__(256) void addf_k(float* __restrict__ out, const float* __restrict__ a,
                                              const float* __restrict__ b, int n) {
    int i = blockIdx.x * blockDim.x + threadIdx.x;
    if (i < n) out[i] = a[i] + b[i];
}

// complex filter per (c,h): (Fr+iFi)*(Wr+iWi)
__global__ __launch_bounds__(256) void filter_k(float* __restrict__ buf, const float* __restrict__ Wr,
                                                const float* __restrict__ Wi, int H, int stride) {
    size_t i = (size_t)blockIdx.x * blockDim.x + threadIdx.x;
    if (i >= (size_t)RROWS * H) return;
    int h = (int)(i % H);
    size_t r = i / H;
    int c = (int)((r >> 9) & 31);
    float* base = buf + r * stride;
    float fr = base[h], fi = base[H + h];
    float wr = Wr[c * H + h];
    float wi = Wi[c * H + h];
    base[h]     = fr * wr - fi * wi;
    base[H + h] = fr * wi + fi * wr;
}

// ---------------- orchestration ----------------
extern "C" void kernel_launch(void* const* d_in, const int* in_sizes, int n_in,
                              void* d_out, int out_size, void* d_ws, size_t ws_size,
                              hipStream_t stream)
{
    const float* x   = (const float*)d_in[0];
    const float* Gc  = (const float*)d_in[3];
    const float* Lc  = (const float*)d_in[4];
    const float* Gt  = (const float*)d_in[5];
    const float* Lt  = (const float*)d_in[6];
    const float* f1r = (const float*)d_in[7];
    const float* f1i = (const float*)d_in[8];
    const float* f2r = (const float*)d_in[9];
    const float* f2i = (const float*)d_in[10];
    const float* Wfc = (const float*)d_in[11];
    const float* bfc = (const float*)d_in[12];
    const float* mi1 = (const float*)d_in[13];
    const float* mi2 = (const float*)d_in[14];
    const float* mo1 = (const float*)d_in[15];
    const float* mo2 = (const float*)d_in[16];
    const float* aiq = (const float*)d_in[17];
    const float* aik = (const float*)d_in[18];
    const float* aoq = (const float*)d_in[19];
    const float* aok = (const float*)d_in[20];
    float* out = (float*)d_out;

    float* w = (float*)d_ws;
    size_t off = 0;
    auto alloc = [&](size_t nf) { float* p = w + off; off += (nf + 255) & ~(size_t)255; return p; };
    float* rf192  = alloc(192 * 194);
    float* irf192 = alloc(194 * 192);
    float* rf96   = alloc(96 * 98);
    float* irf96  = alloc(98 * 96);
    float* feat   = alloc((size_t)16 * 192 * 32);
    float* qb     = alloc((size_t)16 * 192 * 64);
    float* kb     = alloc((size_t)16 * 192 * 64);
    float* gate   = alloc((size_t)16 * 192);
    float* buf1   = alloc((size_t)RROWS * 194);
    float* buf2   = alloc((size_t)RROWS * 194);
    float* buf3   = alloc((size_t)RROWS * 194);
    if (ws_size < off * sizeof(float)) return;  // fail visibly rather than corrupt

    dim3 blk(256);
    auto ggrid = [](int Nc) { return dim3((unsigned)((Nc + 63) / 64), (unsigned)(RROWS / 64)); };

    init_tables_k<<<(93312 + 255) / 256, 256, 0, stream>>>(rf192, irf192, rf96, irf96);

    auto gate_pipeline = [&](float* zbuf, int T, const float* Wq, const float* Wk) {
        meanf_k<<<RB * RC, 256, 0, stream>>>(zbuf, feat, T);
        qk_k<<<(16 * T * 64 + 255) / 256, 256, 0, stream>>>(feat, Wq, Wk, qb, kb, T);
        gate_k<<<16 * T, 64, 0, stream>>>(qb, kb, gate, T);
        scale_k<<<(unsigned)(((size_t)RROWS * T + 255) / 256), 256, 0, stream>>>(zbuf, gate, T);
    };

    // 1: spectra of x
    gemm_k<false, 0><<<ggrid(194), blk, 0, stream>>>(x, rf192, nullptr, buf1, nullptr, RROWS, 194, 192);
    // 2: channel->latent mixing
    chanmix_k<<<(RB * RN * 97 + 127) / 128, 128, 0, stream>>>(buf1, buf2, Gc, Lc, Gt, Lt);
    // 3: x_c = x + irfft
    gemm_k<false, 1><<<ggrid(192), blk, 0, stream>>>(buf2, irf192, nullptr, buf3, x, RROWS, 192, 194);
    // 4-7: input gMLP layers + gates
    gemm_k<true, 0><<<ggrid(192), blk, 0, stream>>>(buf3, mi1, mi2, buf1, nullptr, RROWS, 192, 192);
    gate_pipeline(buf1, 192, aiq, aik);
    gemm_k<true, 0><<<ggrid(192), blk, 0, stream>>>(buf1, mi1 + 192 * 192, mi2 + 192 * 192, buf2, nullptr, RROWS, 192, 192);
    gate_pipeline(buf2, 192, aiq + 2048, aik + 2048);
    // 8: fconv1: rfft(x + x_c)
    addf_k<<<(RROWS * 192 + 255) / 256, 256, 0, stream>>>(buf1, x, buf2, RROWS * 192);
    gemm_k<false, 0><<<ggrid(194), blk, 0, stream>>>(buf1, rf192, nullptr, buf3, nullptr, RROWS, 194, 192);
    filter_k<<<(unsigned)(((size_t)RROWS * 97 + 255) / 256), 256, 0, stream>>>(buf3, f1r, f1i, 97, 194);
    gemm_k<false, 0><<<ggrid(192), blk, 0, stream>>>(buf3, irf192, nullptr, buf1, nullptr, RROWS, 192, 194);
    // 11: h_y = h_x @ Wfc + b
    gemm_k<false, 2><<<ggrid(96), blk, 0, stream>>>(buf1, Wfc, nullptr, buf2, bfc, RROWS, 96, 192);
    // 12-13: output gMLP layers + gates
    gemm_k<true, 0><<<ggrid(96), blk, 0, stream>>>(buf2, mo1, mo2, buf1, nullptr, RROWS, 96, 96);
    gate_pipeline(buf1, 96, aoq, aok);
    gemm_k<true, 0><<<ggrid(96), blk, 0, stream>>>(buf1, mo1 + 96 * 96, mo2 + 96 * 96, buf3, nullptr, RROWS, 96, 96);
    gate_pipeline(buf3, 96, aoq + 2048, aok + 2048);
    // 14-16: fconv2 -> output
    addf_k<<<(RROWS * 96 + 255) / 256, 256, 0, stream>>>(buf1, buf2, buf3, RROWS * 96);
    gemm_k<false, 0><<<ggrid(98), blk, 0, stream>>>(buf1, rf96, nullptr, buf2, nullptr, RROWS, 98, 96);
    filter_k<<<(unsigned)(((size_t)RROWS * 49 + 255) / 256), 256, 0, stream>>>(buf2, f2r, f2i, 49, 98);
    gemm_k<false, 0><<<ggrid(96), blk, 0, stream>>>(buf2, irf96, nullptr, out, nullptr, RROWS, 96, 98);
}

// Round 3
// 1979.875 us; speedup vs baseline: 2.9946x; 2.9946x over previous
//
#include <hip/hip_runtime.h>
#include <hip/hip_bf16.h>

#define RB 16
#define RC 32
#define RN 512
#define RROWS (RB*RC*RN)   // 262144

typedef __attribute__((ext_vector_type(8))) short short8;
typedef __attribute__((ext_vector_type(4))) float floatx4;

__device__ __forceinline__ float bf2f(short s) {
    unsigned u = ((unsigned)(unsigned short)s) << 16;
    float f; __builtin_memcpy(&f, &u, 4); return f;
}
__device__ __forceinline__ short f2bf(float f) {
    __hip_bfloat16 h = __float2bfloat16(f);
    short s; __builtin_memcpy(&s, &h, 2); return s;
}
__device__ __forceinline__ float gelu_tanh(float x) {
    float u = 0.7978845608028654f * (x + 0.044715f * x * x * x);
    return 0.5f * x * (1.0f + tanhf(u));
}

// ---------------- input conversion ----------------
__global__ __launch_bounds__(256) void convert_x_k(const float* __restrict__ x, short* __restrict__ xb) {
    size_t i = ((size_t)blockIdx.x * 256 + threadIdx.x) * 4;
    if (i >= (size_t)RROWS * 192) return;
    const float4 v = *(const float4*)(x + i);
    xb[i + 0] = f2bf(v.x); xb[i + 1] = f2bf(v.y);
    xb[i + 2] = f2bf(v.z); xb[i + 3] = f2bf(v.w);
}

// ---------------- B^T tables/weights prep (bf16) ----------------
// layout (bf16 elems):
//   rfBT192  [256][192] @ 0        (rows: 0..96 cos, 97..193 -sin, rest 0)
//   irfBT192 [192][224] @ 49152    (cols: 0..96 w*cos/192, 97..193 -w*sin/192, rest 0)
//   rfBT96   [128][96]  @ 92160
//   irfBT96  [128][128] @ 104448
//   miT1 [2][192][192] @ 120832 ; miT2 @ 194560
//   moT1 [2][128][96]  @ 268288 ; moT2 @ 292864
//   WfcT [128][192]    @ 317440  (total 342016)
__global__ __launch_bounds__(256) void prep_k(short* __restrict__ tabs,
    const float* __restrict__ mi1, const float* __restrict__ mi2,
    const float* __restrict__ mo1, const float* __restrict__ mo2,
    const float* __restrict__ Wfc)
{
    int i = blockIdx.x * 256 + threadIdx.x;
    const float PI2 = 6.283185307179586f;
    float v = 0.f;
    if (i < 49152) {
        int n = i / 192, t = i % 192;
        if (n < 97) { float s, c; sincosf(PI2 * (float)((n * t) % 192) / 192.f, &s, &c); v = c; }
        else if (n < 194) { int h = n - 97; float s, c; sincosf(PI2 * (float)((h * t) % 192) / 192.f, &s, &c); v = -s; }
        tabs[i] = f2bf(v);
    } else if (i < 92160) {
        int j = i - 49152; int t = j / 224, k = j % 224;
        if (k < 97) { float w = (k == 0 || k == 96) ? 1.f : 2.f; float s, c; sincosf(PI2 * (float)((k * t) % 192) / 192.f, &s, &c); v = w * c / 192.f; }
        else if (k < 194) { int h = k - 97; float w = (h == 0 || h == 96) ? 1.f : 2.f; float s, c; sincosf(PI2 * (float)((h * t) % 192) / 192.f, &s, &c); v = -w * s / 192.f; }
        tabs[i] = f2bf(v);
    } else if (i < 104448) {
        int j = i - 92160; int n = j / 96, t = j % 96;
        if (n < 49) { float s, c; sincosf(PI2 * (float)((n * t) % 96) / 96.f, &s, &c); v = c; }
        else if (n < 98) { int h = n - 49; float s, c; sincosf(PI2 * (float)((h * t) % 96) / 96.f, &s, &c); v = -s; }
        tabs[i] = f2bf(v);
    } else if (i < 120832) {
        int j = i - 104448; int t = j / 128, k = j % 128;
        if (t < 96) {
            if (k < 49) { float w = (k == 0 || k == 48) ? 1.f : 2.f; float s, c; sincosf(PI2 * (float)((k * t) % 96) / 96.f, &s, &c); v = w * c / 96.f; }
            else if (k < 98) { int h = k - 49; float w = (h == 0 || h == 48) ? 1.f : 2.f; float s, c; sincosf(PI2 * (float)((h * t) % 96) / 96.f, &s, &c); v = -w * s / 96.f; }
        }
        tabs[i] = f2bf(v);
    } else if (i < 194560) {
        int j = i - 120832; int l = j / 36864, r = j % 36864, s_ = r / 192, t = r % 192;
        tabs[i] = f2bf(mi1[l * 36864 + t * 192 + s_]);
    } else if (i < 268288) {
        int j = i - 194560; int l = j / 36864, r = j % 36864, s_ = r / 192, t = r % 192;
        tabs[i] = f2bf(mi2[l * 36864 + t * 192 + s_]);
    } else if (i < 292864) {
        int j = i - 268288; int l = j / 12288, r = j % 12288, s_ = r / 96, t = r % 96;
        tabs[i] = f2bf(s_ < 96 ? mo1[l * 9216 + t * 96 + s_] : 0.f);
    } else if (i < 317440) {
        int j = i - 292864; int l = j / 12288, r = j % 12288, s_ = r / 96, t = r % 96;
        tabs[i] = f2bf(s_ < 96 ? mo2[l * 9216 + t * 96 + s_] : 0.f);
    } else if (i < 342016) {
        int j = i - 317440; int s_ = j / 192, t = j % 192;
        tabs[i] = f2bf(s_ < 96 ? Wfc[t * 96 + s_] : 0.f);
    }
}

// ---------------- MFMA GEMM, C[M x Nc] = A[M x K] @ BT[n][k]^T ----------------
// block tile 128x64, 4 waves (2x2), wave tile 64x32, mfma 16x16x32 bf16.
// A stride == K (bf16). BT row stride == K (bf16), rows padded to 64*gridx, pad rows zero.
// DUAL: C = (A@B1) * gelu(A@B2).  ASUM: A = A1 + A2 elementwise (staged).
// EPI: 0 bf16 store; 1 += bf16 X[M x Nc]; 2 += f32 bias X[Nc]; 3 fp32 store.
template<bool DUAL, bool ASUM, int EPI>
__global__ __launch_bounds__(256) void gemm_bt_k(
    const short* __restrict__ A1, const short* __restrict__ A2,
    const short* __restrict__ BT1, const short* __restrict__ BT2,
    void* __restrict__ Cp, const void* __restrict__ Xp,
    int Nc, int K, int ldc)
{
    __shared__ short As[128 * 40];
    __shared__ short Bs1[64 * 40];
    __shared__ short Bs2[DUAL ? 64 * 40 : 8];

    const int tid = threadIdx.x;
    const int wid = tid >> 6, lane = tid & 63;
    const int wm = wid >> 1, wn = wid & 1;
    const int quad = lane >> 4, cl = lane & 15;
    const int m0 = blockIdx.y * 128, n0 = blockIdx.x * 64;

    floatx4 acc[4][2] = {};
    floatx4 acc2[4][2] = {};

    for (int k0 = 0; k0 < K; k0 += 32) {
        #pragma unroll
        for (int j = 0; j < 2; ++j) {
            int idx = tid + j * 256;
            int r = idx >> 2, kc = (idx & 3) << 3;
            short8 va = *(const short8*)(A1 + (size_t)(m0 + r) * K + k0 + kc);
            if (ASUM) {
                const short8 vb = *(const short8*)(A2 + (size_t)(m0 + r) * K + k0 + kc);
                #pragma unroll
                for (int e = 0; e < 8; ++e) va[e] = f2bf(bf2f(va[e]) + bf2f(vb[e]));
            }
            *(short8*)(As + r * 40 + kc) = va;
        }
        {
            int n = tid >> 2, kc = (tid & 3) << 3;
            *(short8*)(Bs1 + n * 40 + kc) = *(const short8*)(BT1 + (size_t)(n0 + n) * K + k0 + kc);
            if (DUAL)
                *(short8*)(Bs2 + n * 40 + kc) = *(const short8*)(BT2 + (size_t)(n0 + n) * K + k0 + kc);
        }
        __syncthreads();

        short8 af[4], bfa[2], bfb[2];
        #pragma unroll
        for (int mf = 0; mf < 4; ++mf)
            af[mf] = *(const short8*)(As + (wm * 64 + mf * 16 + cl) * 40 + quad * 8);
        #pragma unroll
        for (int nf = 0; nf < 2; ++nf) {
            bfa[nf] = *(const short8*)(Bs1 + (wn * 32 + nf * 16 + cl) * 40 + quad * 8);
            if (DUAL) bfb[nf] = *(const short8*)(Bs2 + (wn * 32 + nf * 16 + cl) * 40 + quad * 8);
        }
        #pragma unroll
        for (int mf = 0; mf < 4; ++mf)
            #pragma unroll
            for (int nf = 0; nf < 2; ++nf) {
                acc[mf][nf] = __builtin_amdgcn_mfma_f32_16x16x32_bf16(af[mf], bfa[nf], acc[mf][nf], 0, 0, 0);
                if (DUAL)
                    acc2[mf][nf] = __builtin_amdgcn_mfma_f32_16x16x32_bf16(af[mf], bfb[nf], acc2[mf][nf], 0, 0, 0);
            }
        __syncthreads();
    }

    #pragma unroll
    for (int mf = 0; mf < 4; ++mf) {
        #pragma unroll
        for (int nf = 0; nf < 2; ++nf) {
            int col = n0 + wn * 32 + nf * 16 + cl;
            if (col >= Nc) continue;
            #pragma unroll
            for (int r = 0; r < 4; ++r) {
                int row = m0 + wm * 64 + mf * 16 + quad * 4 + r;
                float v = acc[mf][nf][r];
                if (DUAL) v *= gelu_tanh(acc2[mf][nf][r]);
                size_t idx = (size_t)row * ldc + col;
                if (EPI == 1) v += bf2f(((const short*)Xp)[idx]);
                if (EPI == 2) v += ((const float*)Xp)[col];
                if (EPI == 3) ((float*)Cp)[idx] = v;
                else          ((short*)Cp)[idx] = f2bf(v);
            }
        }
    }
}

// ---------------- channel->latent spectral mixing (bf16 buffers) ----------------
__global__ __launch_bounds__(128) void chanmix_k(
    const short* __restrict__ Fin, short* __restrict__ Fout,
    const float* __restrict__ Gc, const float* __restrict__ Lc,
    const float* __restrict__ Gt, const float* __restrict__ Lt)
{
    __shared__ float sGc[1024], sGt[1024];
    for (int j = threadIdx.x; j < 1024; j += 128) { sGc[j] = Gc[j]; sGt[j] = Gt[j]; }
    __syncthreads();

    int i = blockIdx.x * blockDim.x + threadIdx.x;
    if (i >= RB * RN * 97) return;
    int h = i % 97; int n = (i / 97) % RN; int b = i / (97 * RN);
    size_t base = ((size_t)b * RC * RN + n) * 224;
    const size_t cs = (size_t)RN * 224;

    float acc[32];
    #pragma unroll
    for (int l = 0; l < 32; ++l) acc[l] = 0.f;
    for (int c = 0; c < 32; ++c) {
        float v = bf2f(Fin[base + (size_t)c * cs + h]);
        #pragma unroll
        for (int l = 0; l < 32; ++l) acc[l] += v * sGc[c * 32 + l];
    }
    #pragma unroll
    for (int l = 0; l < 32; ++l)
        Fout[base + (size_t)l * cs + h] = f2bf(acc[l] * Lc[l * 97 + h]);

    #pragma unroll
    for (int l = 0; l < 32; ++l) acc[l] = 0.f;
    for (int c = 0; c < 32; ++c) {
        float v = bf2f(Fin[base + (size_t)c * cs + 97 + h]);
        #pragma unroll
        for (int l = 0; l < 32; ++l) acc[l] += v * sGt[c * 32 + l];
    }
    #pragma unroll
    for (int l = 0; l < 32; ++l)
        Fout[base + (size_t)l * cs + 97 + h] = f2bf(acc[l] * Lt[l * 97 + h]);
}

// ---------------- attn-gate pipeline ----------------
__global__ __launch_bounds__(256) void meanf_k(const short* __restrict__ z, float* __restrict__ feat, int T) {
    int bc = blockIdx.x; int b = bc >> 5, c = bc & 31;
    int t = threadIdx.x; if (t >= T) return;
    const short* p = z + (size_t)bc * RN * T + t;
    float acc = 0.f;
    #pragma unroll 8
    for (int n = 0; n < RN; ++n) acc += bf2f(p[(size_t)n * T]);
    feat[((size_t)b * T + t) * 32 + c] = acc * (1.0f / RN);
}

__global__ __launch_bounds__(256) void qk_k(const float* __restrict__ feat,
    const float* __restrict__ Wq, const float* __restrict__ Wk,
    float* __restrict__ qb, float* __restrict__ kb, int T)
{
    int i = blockIdx.x * blockDim.x + threadIdx.x;
    if (i >= 16 * T * 64) return;
    int e = i & 63; int t = (i >> 6) % T; int b = i / (64 * T);
    const float* f = feat + ((size_t)b * T + t) * 32;
    float q = 0.f, k = 0.f;
    #pragma unroll
    for (int c = 0; c < 32; ++c) {
        float fv = f[c];
        q += fv * Wq[c * 64 + e];
        k += fv * Wk[c * 64 + e];
    }
    qb[i] = q; kb[i] = k;
}

__global__ __launch_bounds__(64) void gate_k(const float* __restrict__ qb, const float* __restrict__ kb,
                                             float* __restrict__ gate, int T)
{
    __shared__ float s[192];
    int b = blockIdx.x / T, t = blockIdx.x % T;
    int lane = threadIdx.x;
    float qe = qb[((size_t)b * T + t) * 64 + lane];
    for (int t2 = 0; t2 < T; ++t2) {
        float prod = qe * kb[((size_t)b * T + t2) * 64 + lane];
        #pragma unroll
        for (int off = 32; off > 0; off >>= 1) prod += __shfl_xor(prod, off);
        if (lane == 0) s[t2] = prod * 0.125f;
    }
    __syncthreads();
    float m = -1e30f;
    for (int t2 = lane; t2 < T; t2 += 64) m = fmaxf(m, s[t2]);
    #pragma unroll
    for (int off = 32; off > 0; off >>= 1) m = fmaxf(m, __shfl_xor(m, off));
    float sum = 0.f;
    for (int t2 = lane; t2 < T; t2 += 64) sum += __expf(s[t2] - m);
    #pragma unroll
    for (int off = 32; off > 0; off >>= 1) sum += __shfl_xor(sum, off);
    if (lane == 0) {
        float wv = __expf(s[t] - m) / sum;
        gate[b * T + t] = 1.0f + gelu_tanh(wv);
    }
}

__global__ __launch_bounds__(256) void scale_k(short* __restrict__ z, const float* __restrict__ gate, int T) {
    size_t i = ((size_t)blockIdx.x * blockDim.x + threadIdx.x) * 2;
    if (i >= (size_t)RROWS * T) return;
    int t = (int)(i % T);
    int b = (int)(i / ((size_t)T * RC * RN));
    z[i]     = f2bf(bf2f(z[i])     * gate[b * T + t]);
    z[i + 1] = f2bf(bf2f(z[i + 1]) * gate[b * T + t + 1]);
}

// complex filter per (c,h): (Fr+iFi)*(Wr+iWi), bf16 buffer, fp32 weights
__global__ __launch_bounds__(256) void filter_k(short* __restrict__ buf, const float* __restrict__ Wr,
                                                const float* __restrict__ Wi, int H, int stride) {
    size_t i = (size_t)blockIdx.x * blockDim.x + threadIdx.x;
    if (i >= (size_t)RROWS * H) return;
    int h = (int)(i % H);
    size_t r = i / H;
    int c = (int)((r >> 9) & 31);
    short* base = buf + r * stride;
    float fr = bf2f(base[h]), fi = bf2f(base[H + h]);
    float wr = Wr[c * H + h];
    float wi = Wi[c * H + h];
    base[h]     = f2bf(fr * wr - fi * wi);
    base[H + h] = f2bf(fr * wi + fi * wr);
}

// ---------------- orchestration ----------------
extern "C" void kernel_launch(void* const* d_in, const int* in_sizes, int n_in,
                              void* d_out, int out_size, void* d_ws, size_t ws_size,
                              hipStream_t stream)
{
    const float* x   = (const float*)d_in[0];
    const float* Gc  = (const float*)d_in[3];
    const float* Lc  = (const float*)d_in[4];
    const float* Gt  = (const float*)d_in[5];
    const float* Lt  = (const float*)d_in[6];
    const float* f1r = (const float*)d_in[7];
    const float* f1i = (const float*)d_in[8];
    const float* f2r = (const float*)d_in[9];
    const float* f2i = (const float*)d_in[10];
    const float* Wfc = (const float*)d_in[11];
    const float* bfc = (const float*)d_in[12];
    const float* mi1 = (const float*)d_in[13];
    const float* mi2 = (const float*)d_in[14];
    const float* mo1 = (const float*)d_in[15];
    const float* mo2 = (const float*)d_in[16];
    const float* aiq = (const float*)d_in[17];
    const float* aik = (const float*)d_in[18];
    const float* aoq = (const float*)d_in[19];
    const float* aok = (const float*)d_in[20];

    // fp32 scratch
    float* wf = (float*)d_ws;
    size_t fo = 0;
    auto falloc = [&](size_t nf) { float* p = wf + fo; fo += (nf + 3) & ~(size_t)3; return p; };
    float* feat = falloc((size_t)16 * 192 * 32);
    float* qb   = falloc((size_t)16 * 192 * 64);
    float* kb   = falloc((size_t)16 * 192 * 64);
    float* gate = falloc((size_t)16 * 192);
    // bf16 scratch
    short* wb = (short*)(wf + fo);
    size_t bo = 0;
    auto balloc = [&](size_t ne) { short* p = wb + bo; bo += (ne + 7) & ~(size_t)7; return p; };
    short* tabs = balloc(342016);
    short* xb   = balloc((size_t)RROWS * 192);
    short* buf1 = balloc((size_t)RROWS * 224);
    short* buf2 = balloc((size_t)RROWS * 224);
    short* buf3 = balloc((size_t)RROWS * 224);
    if (ws_size < fo * sizeof(float) + bo * sizeof(short)) return;

    short* rfBT192  = tabs;
    short* irfBT192 = tabs + 49152;
    short* rfBT96   = tabs + 92160;
    short* irfBT96  = tabs + 104448;
    short* miT1     = tabs + 120832;
    short* miT2     = tabs + 194560;
    short* moT1     = tabs + 268288;
    short* moT2     = tabs + 292864;
    short* WfcT     = tabs + 317440;

    convert_x_k<<<(RROWS * 192 / 4 + 255) / 256, 256, 0, stream>>>(x, xb);
    prep_k<<<(342016 + 255) / 256, 256, 0, stream>>>(tabs, mi1, mi2, mo1, mo2, Wfc);

    auto gate_pipeline = [&](short* zbuf, int T, const float* Wq, const float* Wk) {
        meanf_k<<<RB * RC, 256, 0, stream>>>(zbuf, feat, T);
        qk_k<<<(16 * T * 64 + 255) / 256, 256, 0, stream>>>(feat, Wq, Wk, qb, kb, T);
        gate_k<<<16 * T, 64, 0, stream>>>(qb, kb, gate, T);
        scale_k<<<(unsigned)(((size_t)RROWS * T / 2 + 255) / 256), 256, 0, stream>>>(zbuf, gate, T);
    };

    // 1: spectra of x -> buf1 (stride 224)
    gemm_bt_k<false, false, 0><<<dim3(4, 2048), 256, 0, stream>>>(xb, nullptr, rfBT192, nullptr, buf1, nullptr, 194, 192, 224);
    // 2: channel->latent mixing -> buf2
    chanmix_k<<<(RB * RN * 97 + 127) / 128, 128, 0, stream>>>(buf1, buf2, Gc, Lc, Gt, Lt);
    // 3: x_c = x + irfft -> buf3 (stride 192)
    gemm_bt_k<false, false, 1><<<dim3(3, 2048), 256, 0, stream>>>(buf2, nullptr, irfBT192, nullptr, buf3, xb, 192, 224, 192);
    // 4-7: input gMLP layers + gates
    gemm_bt_k<true, false, 0><<<dim3(3, 2048), 256, 0, stream>>>(buf3, nullptr, miT1, miT2, buf1, nullptr, 192, 192, 192);
    gate_pipeline(buf1, 192, aiq, aik);
    gemm_bt_k<true, false, 0><<<dim3(3, 2048), 256, 0, stream>>>(buf1, nullptr, miT1 + 36864, miT2 + 36864, buf2, nullptr, 192, 192, 192);
    gate_pipeline(buf2, 192, aiq + 2048, aik + 2048);
    // 8: fconv1 rfft(x + x_c) -> buf3 (stride 224)
    gemm_bt_k<false, true, 0><<<dim3(4, 2048), 256, 0, stream>>>(xb, buf2, rfBT192, nullptr, buf3, nullptr, 194, 192, 224);
    filter_k<<<(unsigned)(((size_t)RROWS * 97 + 255) / 256), 256, 0, stream>>>(buf3, f1r, f1i, 97, 224);
    // 10: h_x = irfft -> buf1 (stride 192)
    gemm_bt_k<false, false, 0><<<dim3(3, 2048), 256, 0, stream>>>(buf3, nullptr, irfBT192, nullptr, buf1, nullptr, 192, 224, 192);
    // 11: h_y = h_x @ Wfc + b -> buf2 (stride 96)
    gemm_bt_k<false, false, 2><<<dim3(2, 2048), 256, 0, stream>>>(buf1, nullptr, WfcT, nullptr, buf2, bfc, 96, 192, 96);
    // 12-13: output gMLP layers + gates
    gemm_bt_k<true, false, 0><<<dim3(2, 2048), 256, 0, stream>>>(buf2, nullptr, moT1, moT2, buf1, nullptr, 96, 96, 96);
    gate_pipeline(buf1, 96, aoq, aok);
    gemm_bt_k<true, false, 0><<<dim3(2, 2048), 256, 0, stream>>>(buf1, nullptr, moT1 + 12288, moT2 + 12288, buf3, nullptr, 96, 96, 96);
    gate_pipeline(buf3, 96, aoq + 2048, aok + 2048);
    // 14: fconv2 rfft(h_y + y_c) -> buf1 (stride 128)
    gemm_bt_k<false, true, 0><<<dim3(2, 2048), 256, 0, stream>>>(buf2, buf3, rfBT96, nullptr, buf1, nullptr, 98, 96, 128);
    filter_k<<<(unsigned)(((size_t)RROWS * 49 + 255) / 256), 256, 0, stream>>>(buf1, f2r, f2i, 49, 128);
    // 16: irfft -> d_out (fp32)
    gemm_bt_k<false, false, 3><<<dim3(2, 2048), 256, 0, stream>>>(buf1, nullptr, irfBT96, nullptr, d_out, nullptr, 96, 128, 96);
}